// Round 4
// baseline (162.597 us; speedup 1.0000x reference)
//
#include <hip/hip_runtime.h>
#include <hip/hip_bf16.h>

#define NG 128
#define KTOP 4
#define THREADS 512
#define WAVES (THREADS / 64)
#define T 4                       // truths per block

// lexicographic "better": higher IoU wins; exact fp32 tie -> lower index wins
__device__ __forceinline__ bool better(float va, int ia, float vb, int ib) {
    return (va > vb) || (va == vb && ia < ib);
}

__global__ __launch_bounds__(THREADS)
void ptl_topk_encode_kernel(const float* __restrict__ rois,    // (B,2,P,4) f32
                            const float* __restrict__ targets, // (B,G,4)  f32
                            float* __restrict__ out,           // (B, G*K, 4) f32
                            int P, int nblocks)
{
    #pragma clang fp contract(off)

    const int blk = blockIdx.x;
    if (blk >= nblocks) return;
    const int bpb   = NG / T;                 // blocks per batch = 32
    const int b     = blk / bpb;
    const int gbase = (blk % bpb) * T;

    // defaults = rpn_rois[:, 1]
    const float*  priors = rois + ((size_t)(2 * b + 1)) * (size_t)P * 4u;
    const float4* pv     = (const float4*)priors;

    // truth coords for T truths
    float tt0[T], tt1[T], tt2[T], tt3[T], areaT[T];
    #pragma unroll
    for (int t = 0; t < T; ++t) {
        const float* tp = targets + ((size_t)(b * NG + gbase + t)) * 4u;
        tt0[t] = tp[0]; tt1[t] = tp[1]; tt2[t] = tp[2]; tt3[t] = tp[3];
        areaT[t] = (tt2[t] - tt0[t]) * (tt3[t] - tt1[t]);
    }

    // per-thread top-4 state per truth, sorted descending, stable
    float v0[T], v1[T], v2[T], v3[T];
    int   j0[T], j1[T], j2[T], j3[T];
    #pragma unroll
    for (int t = 0; t < T; ++t) {
        v0[t] = v1[t] = v2[t] = v3[t] = -1.f;
        j0[t] = j1[t] = j2[t] = j3[t] = 0;
    }

    // ---- phase 1: stream priors, branchless stable top-4 insert per truth ----
    for (int i = threadIdx.x; i < P; i += THREADS) {
        float4 q = pv[i];
        float area_p = (q.z - q.x) * (q.w - q.y);

        #pragma unroll
        for (int t = 0; t < T; ++t) {
            // IoU, bit-exact vs numpy fp32 (no contraction, IEEE div, same order)
            float ltx = fmaxf(tt0[t], q.x), lty = fmaxf(tt1[t], q.y);
            float rbx = fminf(tt2[t], q.z), rby = fminf(tt3[t], q.w);
            float wx = fmaxf(rbx - ltx, 0.0f);
            float wy = fmaxf(rby - lty, 0.0f);
            float inter = wx * wy;
            float iou = inter / ((areaT[t] + area_p) - inter);

            // branchless stable insert (strict >, increasing i => stable)
            bool gt0 = iou > v0[t];
            bool gt1 = iou > v1[t];
            bool gt2 = iou > v2[t];
            bool gt3 = iou > v3[t];
            float nv3 = gt2 ? v2[t] : (gt3 ? iou : v3[t]);
            int   nj3 = gt2 ? j2[t] : (gt3 ? i   : j3[t]);
            float nv2 = gt1 ? v1[t] : (gt2 ? iou : v2[t]);
            int   nj2 = gt1 ? j1[t] : (gt2 ? i   : j2[t]);
            float nv1 = gt0 ? v0[t] : (gt1 ? iou : v1[t]);
            int   nj1 = gt0 ? j0[t] : (gt1 ? i   : j1[t]);
            float nv0 = gt0 ? iou   : v0[t];
            int   nj0 = gt0 ? i     : j0[t];
            v0[t]=nv0; v1[t]=nv1; v2[t]=nv2; v3[t]=nv3;
            j0[t]=nj0; j1[t]=nj1; j2[t]=nj2; j3[t]=nj3;
        }
    }

    // ---- phase 2: per-truth tournament (4 rounds of block argmax) ----
    __shared__ float bw_v[WAVES];
    __shared__ int   bw_i[WAVES];
    __shared__ int   bw_t[WAVES];
    __shared__ int   win_tid;

    const int lane = threadIdx.x & 63;
    const int wv   = threadIdx.x >> 6;

    #pragma unroll
    for (int t = 0; t < T; ++t) {
        const float gcx = (tt0[t] + tt2[t]) * 0.5f;
        const float gcy = (tt1[t] + tt3[t]) * 0.5f;
        const float gw  = tt2[t] - tt0[t];
        const float gh  = tt3[t] - tt1[t];

        int p = 0;   // my consumed-entry count for this truth

        for (int k = 0; k < KTOP; ++k) {
            float cv; int ci;
            if      (p == 0) { cv = v0[t]; ci = j0[t]; }
            else if (p == 1) { cv = v1[t]; ci = j1[t]; }
            else if (p == 2) { cv = v2[t]; ci = j2[t]; }
            else if (p == 3) { cv = v3[t]; ci = j3[t]; }
            else             { cv = -2.f;  ci = 0; }
            int ct = threadIdx.x;

            #pragma unroll
            for (int d = 32; d >= 1; d >>= 1) {
                float ov = __shfl_down(cv, d, 64);
                int   oi = __shfl_down(ci, d, 64);
                int   ot = __shfl_down(ct, d, 64);
                if (better(ov, oi, cv, ci)) { cv = ov; ci = oi; ct = ot; }
            }
            if (lane == 0) { bw_v[wv] = cv; bw_i[wv] = ci; bw_t[wv] = ct; }
            __syncthreads();

            if (threadIdx.x == 0) {
                float bv = bw_v[0]; int bi = bw_i[0]; int bt = bw_t[0];
                #pragma unroll
                for (int w = 1; w < WAVES; ++w)
                    if (better(bw_v[w], bw_i[w], bv, bi)) { bv = bw_v[w]; bi = bw_i[w]; bt = bw_t[w]; }
                win_tid = bt;
            }
            __syncthreads();

            if (threadIdx.x == win_tid) {
                int bi;
                if      (p == 0) bi = j0[t];
                else if (p == 1) bi = j1[t];
                else if (p == 2) bi = j2[t];
                else             bi = j3[t];
                bi = min(max(bi, 0), P - 1);   // defensive clamp

                float4 q = pv[bi];
                float pcx = (q.x + q.z) * 0.5f;
                float pcy = (q.y + q.w) * 0.5f;
                float pw  = q.z - q.x;
                float ph  = q.w - q.y;
                float ox = (gcx - pcx) / (0.1f * pw);
                float oy = (gcy - pcy) / (0.1f * ph);
                float ow = logf(gw / pw) / 0.2f;
                float oh = logf(gh / ph) / 0.2f;

                size_t o = (((size_t)(b * NG + gbase + t)) * KTOP + k) * 4;
                out[o + 0] = ox;
                out[o + 1] = oy;
                out[o + 2] = ow;
                out[o + 3] = oh;

                ++p;
            }
            __syncthreads();
        }
    }
}

extern "C" void kernel_launch(void* const* d_in, const int* in_sizes, int n_in,
                              void* d_out, int out_size, void* d_ws, size_t ws_size,
                              hipStream_t stream) {
    const float* rois    = (const float*)d_in[0];
    const float* targets = (const float*)d_in[1];
    float* out = (float*)d_out;

    const int B = in_sizes[1] / (NG * 4);          // 16
    const int P = in_sizes[0] / (B * 2 * 4);       // 32768
    const int nblocks = B * (NG / T);              // 512

    ptl_topk_encode_kernel<<<dim3(nblocks), dim3(THREADS), 0, stream>>>(
        rois, targets, out, P, nblocks);
}

// Round 5
// 161.255 us; speedup vs baseline: 1.0083x; 1.0083x over previous
//
#include <hip/hip_runtime.h>

#define NG 128
#define KTOP 4
#define THREADS 256
#define WAVES 4                 // THREADS / 64
#define T 4                     // truths per block
#define S 4                     // prior segments per (batch, truth-group)
typedef unsigned long long u64;
typedef unsigned int u32;

// compare-exchange, descending: x <- max, y <- min (keys distinct by construction)
__device__ __forceinline__ void ce(u64 &x, u64 &y) {
    u64 a = x, b = y;
    bool gt = a > b;
    x = gt ? a : b;
    y = gt ? b : a;
}

__device__ __forceinline__ float sload(const float* p) {
    // force wave-uniform value into SGPR
    return __uint_as_float(__builtin_amdgcn_readfirstlane(__float_as_uint(*p)));
}

// ---------------- kernel 1: per-(batch,group,seg) top-4 per truth ----------------
__global__ __launch_bounds__(THREADS, 8)
void ptl_phase1(const float* __restrict__ rois,    // (B,2,P,4) f32
                const float* __restrict__ targets, // (B,NG,4)  f32
                u64* __restrict__ ws,              // (B*NG, S, WAVES, KTOP) u64 keys
                int P)
{
    #pragma clang fp contract(off)

    // XCD-aware swizzle: blk%8 ~ XCD; 2 batches per XCD -> 1MB prior set per L2
    const int blk = blockIdx.x;
    const int xcd = blk & 7;
    const int w   = blk >> 3;            // 0..255
    const int b   = xcd * 2 + (w & 1);   // 0..15
    const int r   = w >> 1;              // 0..127
    const int group = r & 31;            // 0..31
    const int seg   = r >> 5;            // 0..3
    const int gbase = group * T;

    const float4* __restrict__ pv =
        (const float4*)(rois + ((size_t)(2 * b + 1)) * (size_t)P * 4u);

    // truth coords (wave-uniform -> SGPR)
    float tt0[T], tt1[T], tt2[T], tt3[T], areaT[T];
    #pragma unroll
    for (int t = 0; t < T; ++t) {
        const float* tp = targets + ((size_t)(b * NG + gbase + t)) * 4u;
        tt0[t] = sload(tp + 0);
        tt1[t] = sload(tp + 1);
        tt2[t] = sload(tp + 2);
        tt3[t] = sload(tp + 3);
        areaT[t] = (tt2[t] - tt0[t]) * (tt3[t] - tt1[t]);
    }

    // per-thread sorted top-4 per truth
    float v0[T], v1[T], v2[T], v3[T];
    int   j0[T], j1[T], j2[T], j3[T];
    #pragma unroll
    for (int t = 0; t < T; ++t) {
        v0[t] = v1[t] = v2[t] = v3[t] = -1.f;
        j0[t] = j1[t] = j2[t] = j3[t] = 0;
    }

    const int segLen  = P / S;                 // 8192
    const int segBase = seg * segLen;
    const int tid     = threadIdx.x;
    const int ITER    = segLen / THREADS;      // 32

    int    idx = segBase + tid;
    float4 q   = pv[idx];

    for (int it = 1; it <= ITER; ++it) {
        float4 qn;
        if (it < ITER) qn = pv[segBase + tid + it * THREADS];   // prefetch (uniform branch)

        float area_p = (q.z - q.x) * (q.w - q.y);
        #pragma unroll
        for (int t = 0; t < T; ++t) {
            // IoU bit-exact vs numpy fp32 (no contraction, IEEE div, same op order)
            float ltx = fmaxf(tt0[t], q.x), lty = fmaxf(tt1[t], q.y);
            float rbx = fminf(tt2[t], q.z), rby = fminf(tt3[t], q.w);
            float wx = fmaxf(rbx - ltx, 0.0f);
            float wy = fmaxf(rby - lty, 0.0f);
            float inter = wx * wy;
            float iou = inter / ((areaT[t] + area_p) - inter);

            // branchless stable insert (strict >, ascending idx => stable)
            bool gt0 = iou > v0[t];
            bool gt1 = iou > v1[t];
            bool gt2 = iou > v2[t];
            bool gt3 = iou > v3[t];
            float nv3 = gt2 ? v2[t] : (gt3 ? iou : v3[t]);
            int   nj3 = gt2 ? j2[t] : (gt3 ? idx : j3[t]);
            float nv2 = gt1 ? v1[t] : (gt2 ? iou : v2[t]);
            int   nj2 = gt1 ? j1[t] : (gt2 ? idx : j2[t]);
            float nv1 = gt0 ? v0[t] : (gt1 ? iou : v1[t]);
            int   nj1 = gt0 ? j0[t] : (gt1 ? idx : j1[t]);
            float nv0 = gt0 ? iou   : v0[t];
            int   nj0 = gt0 ? idx   : j0[t];
            v0[t]=nv0; v1[t]=nv1; v2[t]=nv2; v3[t]=nv3;
            j0[t]=nj0; j1[t]=nj1; j2[t]=nj2; j3[t]=nj3;
        }

        q = qn;
        idx = segBase + tid + it * THREADS;
    }

    // per-wave merge of sorted-4 lists (barrier-free), u64 keys
    const int lane = threadIdx.x & 63;
    const int wv   = threadIdx.x >> 6;
    const size_t tbase = (size_t)(b * NG + gbase);

    #pragma unroll
    for (int t = 0; t < T; ++t) {
        u64 k0 = ((u64)__float_as_uint(v0[t]) << 32) | (u32)(~(u32)j0[t]);
        u64 k1 = ((u64)__float_as_uint(v1[t]) << 32) | (u32)(~(u32)j1[t]);
        u64 k2 = ((u64)__float_as_uint(v2[t]) << 32) | (u32)(~(u32)j2[t]);
        u64 k3 = ((u64)__float_as_uint(v3[t]) << 32) | (u32)(~(u32)j3[t]);

        #pragma unroll
        for (int d = 32; d >= 1; d >>= 1) {
            u64 n0 = __shfl_down(k0, d, 64);
            u64 n1 = __shfl_down(k1, d, 64);
            u64 n2 = __shfl_down(k2, d, 64);
            u64 n3 = __shfl_down(k3, d, 64);
            // bitonic half-cleaner: keep 4 largest of 8 ...
            ce(k0, n3); ce(k1, n2); ce(k2, n1); ce(k3, n0);
            // ... then sort the (bitonic) max-half descending
            ce(k0, k2); ce(k1, k3); ce(k0, k1); ce(k2, k3);
        }

        if (lane == 0) {
            u64* dst = ws + (((tbase + t) * S + seg) * WAVES + wv) * KTOP;
            dst[0] = k0; dst[1] = k1; dst[2] = k2; dst[3] = k3;
        }
    }
}

// ---------------- kernel 2: merge 64 candidates per truth, encode ----------------
__global__ __launch_bounds__(256)
void ptl_phase2(const float* __restrict__ rois,    // (B,2,P,4)
                const float* __restrict__ targets, // (B,NG,4)
                const u64* __restrict__ ws,        // (B*NG, 64)
                float* __restrict__ out,           // (B, NG*KTOP, 4)
                int P, int ntruth)
{
    #pragma clang fp contract(off)

    const int tg = blockIdx.x * 256 + threadIdx.x;   // global truth id
    if (tg >= ntruth) return;
    const int b = tg >> 7;                           // NG = 128

    // top-4 over 64 candidates (keys distinct -> exact stable top-4)
    const u64* cand = ws + (size_t)tg * (S * WAVES * KTOP);
    u64 k0 = 0, k1 = 0, k2 = 0, k3 = 0;
    for (int c = 0; c < S * WAVES * KTOP; ++c) {
        u64 x = cand[c];
        bool g0 = x > k0, g1 = x > k1, g2 = x > k2, g3 = x > k3;
        u64 n3 = g2 ? k2 : (g3 ? x : k3);
        u64 n2 = g1 ? k1 : (g2 ? x : k2);
        u64 n1 = g0 ? k0 : (g1 ? x : k1);
        u64 n0 = g0 ? x  : k0;
        k0 = n0; k1 = n1; k2 = n2; k3 = n3;
    }

    const float* tp = targets + (size_t)tg * 4u;
    const float t0 = tp[0], t1 = tp[1], t2 = tp[2], t3 = tp[3];
    const float gcx = (t0 + t2) * 0.5f;
    const float gcy = (t1 + t3) * 0.5f;
    const float gw  = t2 - t0;
    const float gh  = t3 - t1;

    const float4* __restrict__ pv =
        (const float4*)(rois + ((size_t)(2 * b + 1)) * (size_t)P * 4u);
    float4* __restrict__ o4 = (float4*)out;

    u64 ks[KTOP] = {k0, k1, k2, k3};
    #pragma unroll
    for (int k = 0; k < KTOP; ++k) {
        int idx = (int)(~(u32)ks[k]);    // decode prior index
        idx &= (P - 1);                  // defensive (P is pow2)
        float4 q = pv[idx];
        float pcx = (q.x + q.z) * 0.5f;
        float pcy = (q.y + q.w) * 0.5f;
        float pw  = q.z - q.x;
        float ph  = q.w - q.y;
        float4 r;
        r.x = (gcx - pcx) / (0.1f * pw);
        r.y = (gcy - pcy) / (0.1f * ph);
        r.z = logf(gw / pw) / 0.2f;
        r.w = logf(gh / ph) / 0.2f;
        o4[(size_t)tg * KTOP + k] = r;
    }
}

extern "C" void kernel_launch(void* const* d_in, const int* in_sizes, int n_in,
                              void* d_out, int out_size, void* d_ws, size_t ws_size,
                              hipStream_t stream) {
    const float* rois    = (const float*)d_in[0];
    const float* targets = (const float*)d_in[1];
    float* out = (float*)d_out;
    u64* ws = (u64*)d_ws;

    const int B = in_sizes[1] / (NG * 4);          // 16
    const int P = in_sizes[0] / (B * 2 * 4);       // 32768
    const int ntruth = B * NG;                     // 2048

    const int nblk1 = B * (NG / T) * S;            // 16*32*4 = 2048
    ptl_phase1<<<dim3(nblk1), dim3(THREADS), 0, stream>>>(rois, targets, ws, P);

    const int nblk2 = (ntruth + 255) / 256;        // 8
    ptl_phase2<<<dim3(nblk2), dim3(256), 0, stream>>>(rois, targets, ws, out, P, ntruth);
}